// Round 2
// baseline (28789.297 us; speedup 1.0000x reference)
//
#include <hip/hip_runtime.h>
#include <math.h>

// Problem constants
#define TT    12288            // B*S flattened scan length
#define HH    600
#define GG    1800             // 3*H
#define INP   303
#define INP_P 304              // padded for float4 alignment
#define BB    32
#define SS    384
#define D2    1200             // 2H
#define D4    2400             // 4H (cat dim)

// Scan partitioning: 75 workgroups per chain, 8 hidden elems each -> 24 W_hh rows
#define NWG  75
#define JPW  8
#define ROWS 24

#define SENT 0xAAAAAAAAu       // harness poison pattern reused as "not yet written" sentinel

// ws layout (float offsets)
#define EMB_OFF    0ull
#define WP_OFF     3735552ull          // 12288*304
#define GI_OFF     4282752ull          // + 1800*304
#define HS_OFF     26403808ull
#define Q_OFF      26442208ull
#define CTX_OFF    26480608ull
#define GATED_OFF  26519008ull

// ---------------- K0: build padded emb = [bio_emb[tag], context], and padded W_ih
__global__ void build_emb(const float* __restrict__ ctx, const int* __restrict__ tags,
                          const float* __restrict__ bio, float* __restrict__ emb) {
    int idx = blockIdx.x * 256 + threadIdx.x;
    if (idx >= TT * INP_P) return;
    int row = idx / INP_P;
    int c = idx - row * INP_P;
    float v;
    if (c < 3)        v = bio[tags[row] * 3 + c];
    else if (c < INP) v = ctx[(size_t)row * 300 + (c - 3)];
    else              v = 0.f;
    emb[idx] = v;
}

__global__ void pad_wih(const float* __restrict__ W, float* __restrict__ Wp) {
    int idx = blockIdx.x * 256 + threadIdx.x;
    if (idx >= GG * INP_P) return;
    int r = idx / INP_P, c = idx - r * INP_P;
    Wp[idx] = (c < INP) ? W[(size_t)r * INP + c] : 0.f;
}

// ---------------- K1: gi = emb @ W_ih^T + b_ih   (fp32 tiled GEMM, 64x64 tile, BK=16)
__global__ __launch_bounds__(256) void gemm_gi(const float* __restrict__ A,
                                               const float* __restrict__ Bw,
                                               const float* __restrict__ bias,
                                               float* __restrict__ C) {
    __shared__ float As[16][68];
    __shared__ float Bs[16][68];
    const int tid = threadIdx.x;
    const int bm = blockIdx.x, bn = blockIdx.y;
    const int tx = tid & 15, ty = tid >> 4;
    const int lm = tid >> 2;          // 0..63
    const int lk = (tid & 3) * 4;     // 0,4,8,12
    const int gbase = bn * 64;
    float acc[4][4] = {};
    for (int k0 = 0; k0 < INP_P; k0 += 16) {
        float4 av = *(const float4*)(A + (size_t)(bm * 64 + lm) * INP_P + k0 + lk);
        int grow = gbase + lm;
        float4 bv = make_float4(0.f, 0.f, 0.f, 0.f);
        if (grow < GG) bv = *(const float4*)(Bw + (size_t)grow * INP_P + k0 + lk);
        As[lk + 0][lm] = av.x; As[lk + 1][lm] = av.y; As[lk + 2][lm] = av.z; As[lk + 3][lm] = av.w;
        Bs[lk + 0][lm] = bv.x; Bs[lk + 1][lm] = bv.y; Bs[lk + 2][lm] = bv.z; Bs[lk + 3][lm] = bv.w;
        __syncthreads();
#pragma unroll
        for (int kk = 0; kk < 16; ++kk) {
            float4 a4 = *(const float4*)&As[kk][tx * 4];
            float4 b4 = *(const float4*)&Bs[kk][ty * 4];
            acc[0][0] += a4.x * b4.x; acc[0][1] += a4.x * b4.y; acc[0][2] += a4.x * b4.z; acc[0][3] += a4.x * b4.w;
            acc[1][0] += a4.y * b4.x; acc[1][1] += a4.y * b4.y; acc[1][2] += a4.y * b4.z; acc[1][3] += a4.y * b4.w;
            acc[2][0] += a4.z * b4.x; acc[2][1] += a4.z * b4.y; acc[2][2] += a4.z * b4.z; acc[2][3] += a4.z * b4.w;
            acc[3][0] += a4.w * b4.x; acc[3][1] += a4.w * b4.y; acc[3][2] += a4.w * b4.z; acc[3][3] += a4.w * b4.w;
        }
        __syncthreads();
    }
    int g0 = gbase + ty * 4;
    if (g0 < GG) {
        float4 bi4 = *(const float4*)(bias + g0);
#pragma unroll
        for (int i = 0; i < 4; ++i) {
            float4 v = make_float4(acc[i][0] + bi4.x, acc[i][1] + bi4.y,
                                   acc[i][2] + bi4.z, acc[i][3] + bi4.w);
            *(float4*)(C + (size_t)(bm * 64 + tx * 4 + i) * GG + g0) = v;
        }
    }
}

// ---------------- K2: the two sequential GRU scans.
// Sync protocol: the state history itself is the token. All state rows are
// pre-poisoned to SENT; producers store h with agent-scope (LLC-coherent)
// stores; consumers poll row t-1 word-by-word until non-sentinel. Each word
// is written exactly once -> no parity, no flags, no write-after-read hazard.
__global__ __launch_bounds__(256) void gru_scan(const float* __restrict__ gi,
                                                const float* __restrict__ Whh,
                                                const float* __restrict__ bhh,
                                                float* __restrict__ out) {
    __shared__ float w_lds[ROWS * 600];   // 57.6 KB
    __shared__ float h_lds[600];
    __shared__ float partials[240];
    __shared__ float dots_lds[ROWS];
    __shared__ float gi_lds[ROWS];
    __shared__ float bhh_lds[ROWS];

    const int tid = threadIdx.x;
    const int chain = blockIdx.x / NWG;   // 0 = fwd, 1 = bwd
    const int wg = blockIdx.x % NWG;
    const int j0 = wg * JPW;

    float* statesOut = out + 1200 + (size_t)chain * TT * 600;
    unsigned* statesU = (unsigned*)statesOut;

    // Load W_hh slice: rows {j0..j0+7, 600+j0.., 1200+j0..}
    for (int i = tid; i < ROWS * 600; i += 256) {
        int rr = i / 600, k = i - rr * 600;
        int row = (rr >> 3) * 600 + j0 + (rr & 7);
        w_lds[i] = Whh[(size_t)row * 600 + k];
    }
    if (tid < ROWS) {
        int row = (tid >> 3) * 600 + j0 + (tid & 7);
        bhh_lds[tid] = bhh[row];
    }

    const int rrow = tid / 10;            // 0..23 (valid when tid<240)
    const int ch = tid - rrow * 10;       // 0..9
    const int w2 = tid + 512;
    const int w2c = (w2 < 600) ? w2 : 0;
    int si = 0, bi = 0;

    for (int t = 0; t < TT; ++t) {
        // prefetch this wg's gi slice (depends only on t) — in flight during poll
        float gi_reg = 0.f;
        if (tid < ROWS) {
            int gi_row = (chain == 0) ? t : (bi * SS + (SS - 1) - si);
            gi_reg = gi[(size_t)gi_row * GG + (tid >> 3) * 600 + j0 + (tid & 7)];
        }
        __syncthreads();   // prev iteration's h_lds/gi_lds/dots readers done
        if (t == 0) {
            h_lds[tid] = 0.f;
            h_lds[tid + 256] = 0.f;
            if (w2 < 600) h_lds[w2] = 0.f;
        } else {
            const unsigned* hu = statesU + (size_t)(t - 1) * 600;
            for (;;) {
                unsigned b0 = __hip_atomic_load(hu + tid,       __ATOMIC_RELAXED, __HIP_MEMORY_SCOPE_AGENT);
                unsigned b1 = __hip_atomic_load(hu + tid + 256, __ATOMIC_RELAXED, __HIP_MEMORY_SCOPE_AGENT);
                unsigned b2 = __hip_atomic_load(hu + w2c,       __ATOMIC_RELAXED, __HIP_MEMORY_SCOPE_AGENT);
                if (b0 != SENT && b1 != SENT && (w2 >= 600 || b2 != SENT)) {
                    h_lds[tid] = __uint_as_float(b0);
                    h_lds[tid + 256] = __uint_as_float(b1);
                    if (w2 < 600) h_lds[w2] = __uint_as_float(b2);
                    break;
                }
                __builtin_amdgcn_s_sleep(1);
            }
        }
        __syncthreads();
        // matvec: 24 rows x 600, 10 column-chunk threads per row, float4 LDS reads
        if (tid < 240) {
            const float* wr = w_lds + rrow * 600;
            float4 a4 = make_float4(0.f, 0.f, 0.f, 0.f);
#pragma unroll
            for (int i = 0; i < 15; ++i) {
                int g = (ch + 10 * i) * 4;
                float4 w4 = *(const float4*)(wr + g);
                float4 h4 = *(const float4*)(h_lds + g);
                a4.x += w4.x * h4.x; a4.y += w4.y * h4.y;
                a4.z += w4.z * h4.z; a4.w += w4.w * h4.w;
            }
            partials[tid] = (a4.x + a4.y) + (a4.z + a4.w);
        }
        if (tid < ROWS) gi_lds[tid] = gi_reg;
        __syncthreads();
        if (tid < ROWS) {
            const float* p = partials + tid * 10;
            float s = bhh_lds[tid];
#pragma unroll
            for (int c = 0; c < 10; ++c) s += p[c];
            dots_lds[tid] = s;
        }
        __syncthreads();
        // gates + publish (8 producer lanes of wave 0)
        if (tid < JPW) {
            int jg = j0 + tid;
            float r = 1.f / (1.f + expf(-(gi_lds[tid] + dots_lds[tid])));
            float z = 1.f / (1.f + expf(-(gi_lds[8 + tid] + dots_lds[8 + tid])));
            float n = tanhf(gi_lds[16 + tid] + r * dots_lds[16 + tid]);
            float hnew = (1.f - z) * n + z * h_lds[jg];
            if (__float_as_uint(hnew) == SENT) hnew = __uint_as_float(SENT + 1u); // escape sentinel (1 ulp)
            __hip_atomic_store(statesU + (size_t)t * 600 + jg, __float_as_uint(hnew),
                               __ATOMIC_RELAXED, __HIP_MEMORY_SCOPE_AGENT);
            if (t == TT - 1) out[chain * 600 + jg] = hnew;   // final = [h_f, h_b]
        }
        if (++si == SS) { si = 0; ++bi; }
    }
}

// ---------------- K3a: hs gather + q = hs @ W_lin^T + b_lin
__global__ void attn_qs(const float* __restrict__ Wlin, const float* __restrict__ blin,
                        const float* __restrict__ outp, float* __restrict__ ws) {
    __shared__ float hs_lds[1200];
    const int bi = blockIdx.x, tid = threadIdx.x;
    const float* fwdS = outp + 1200;
    const float* bwdS = outp + 1200 + (size_t)TT * 600;
    size_t row = (size_t)(bi * SS + SS - 1) * 600;
    for (int k = tid; k < 600; k += 256) {
        hs_lds[k] = fwdS[row + k];
        hs_lds[600 + k] = bwdS[row + k];
    }
    __syncthreads();
    float* ws_hs = ws + HS_OFF;
    float* ws_q = ws + Q_OFF;
    for (int k = tid; k < 1200; k += 256) ws_hs[bi * 1200 + k] = hs_lds[k];
    const int wave = tid >> 6, lane = tid & 63;
    for (int o = wave; o < 1200; o += 4) {
        const float* wr = Wlin + (size_t)o * 1200;
        float acc = 0.f;
        for (int k = lane; k < 1200; k += 64) acc += hs_lds[k] * wr[k];
        for (int off = 32; off > 0; off >>= 1) acc += __shfl_down(acc, off);
        if (lane == 0) ws_q[bi * 1200 + o] = acc + blin[o];
    }
}

// ---------------- K3b: logits + softmax + ctx
__global__ void attn_ctx(const float* __restrict__ outp, float* __restrict__ ws) {
    __shared__ float q_lds[1200];
    __shared__ float p_lds[SS];
    __shared__ float red[8];
    const int bi = blockIdx.x, tid = threadIdx.x;
    const float* fwdS = outp + 1200;
    const float* bwdS = outp + 1200 + (size_t)TT * 600;
    const float* ws_q = ws + Q_OFF;
    for (int k = tid; k < 1200; k += 256) q_lds[k] = ws_q[bi * 1200 + k];
    __syncthreads();
    const int wave = tid >> 6, lane = tid & 63;
    for (int s = wave; s < SS; s += 4) {
        size_t base = (size_t)(bi * SS + s) * 600;
        float acc = 0.f;
        for (int k = lane; k < 600; k += 64)
            acc += q_lds[k] * fwdS[base + k] + q_lds[600 + k] * bwdS[base + k];
        for (int off = 32; off > 0; off >>= 1) acc += __shfl_down(acc, off);
        if (lane == 0) p_lds[s] = acc;
    }
    __syncthreads();
    float m = -1e30f;
    for (int i = tid; i < SS; i += 256) m = fmaxf(m, p_lds[i]);
    for (int off = 32; off > 0; off >>= 1) m = fmaxf(m, __shfl_down(m, off));
    if (lane == 0) red[wave] = m;
    __syncthreads();
    m = fmaxf(fmaxf(red[0], red[1]), fmaxf(red[2], red[3]));
    float ssum = 0.f;
    for (int i = tid; i < SS; i += 256) ssum += expf(p_lds[i] - m);
    for (int off = 32; off > 0; off >>= 1) ssum += __shfl_down(ssum, off);
    __syncthreads();
    if (lane == 0) red[wave] = ssum;
    __syncthreads();
    ssum = red[0] + red[1] + red[2] + red[3];
    float inv = 1.f / ssum;
    for (int i = tid; i < SS; i += 256) p_lds[i] = expf(p_lds[i] - m) * inv;
    __syncthreads();
    float* ws_ctx = ws + CTX_OFF;
    size_t rbase = (size_t)bi * SS * 600;
    for (int d = tid; d < 1200; d += 256) {
        const float* Sb = (d < 600) ? (fwdS + d) : (bwdS + d - 600);
        float acc = 0.f;
        for (int s2 = 0; s2 < SS; ++s2) acc += p_lds[s2] * Sb[rbase + (size_t)s2 * 600];
        ws_ctx[bi * 1200 + d] = acc;
    }
}

// ---------------- K3c: g/f gates over cat=[ctx,hs], gated output
__global__ void attn_gate(const float* __restrict__ Wg, const float* __restrict__ bg,
                          const float* __restrict__ Wf, const float* __restrict__ bf,
                          float* __restrict__ ws) {
    __shared__ float cat_lds[2400];
    const int bi = blockIdx.x, tid = threadIdx.x;
    const float* ws_ctx = ws + CTX_OFF;
    const float* ws_hs = ws + HS_OFF;
    for (int k = tid; k < 1200; k += 256) {
        cat_lds[k] = ws_ctx[bi * 1200 + k];
        cat_lds[1200 + k] = ws_hs[bi * 1200 + k];
    }
    __syncthreads();
    float* ws_g = ws + GATED_OFF;
    const int wave = tid >> 6, lane = tid & 63;
    for (int o = wave; o < 1200; o += 4) {
        const float* wg = Wg + (size_t)o * D4;
        const float* wf = Wf + (size_t)o * D4;
        float ag = 0.f, af = 0.f;
        for (int k = lane; k < D4; k += 64) {
            float c = cat_lds[k];
            ag += c * wg[k];
            af += c * wf[k];
        }
        for (int off = 32; off > 0; off >>= 1) {
            ag += __shfl_down(ag, off);
            af += __shfl_down(af, off);
        }
        if (lane == 0) {
            float g = 1.f / (1.f + expf(-(ag + bg[o])));
            float f = tanhf(af + bf[o]);
            ws_g[bi * 1200 + o] = g * f + (1.f - g) * cat_lds[1200 + o];
        }
    }
}

// ---------------- K3d: broadcast gated -> attn output (overwrites the states scratch)
__global__ void bcast_attn(const float* __restrict__ ws, float* __restrict__ outp) {
    int idx = blockIdx.x * 256 + threadIdx.x;     // float4 index, exactly 3686400
    const float4* g4 = (const float4*)(ws + GATED_OFF);
    float4* o4 = (float4*)outp;
    int row = idx / 300;          // bi*384+si
    int d4 = idx - row * 300;
    int bi = row / SS;
    o4[300 + idx] = g4[bi * 300 + d4];
}

extern "C" void kernel_launch(void* const* d_in, const int* in_sizes, int n_in,
                              void* d_out, int out_size, void* d_ws, size_t ws_size,
                              hipStream_t stream) {
    const float* ctx   = (const float*)d_in[0];
    const int*   tags  = (const int*)d_in[1];
    const float* bio   = (const float*)d_in[2];
    const float* W_ih  = (const float*)d_in[3];
    const float* b_ih  = (const float*)d_in[4];
    const float* W_hh  = (const float*)d_in[5];
    const float* b_hh  = (const float*)d_in[6];
    const float* W_lin = (const float*)d_in[7];
    const float* b_lin = (const float*)d_in[8];
    const float* W_g   = (const float*)d_in[9];
    const float* b_g   = (const float*)d_in[10];
    const float* W_f   = (const float*)d_in[11];
    const float* b_f   = (const float*)d_in[12];
    float* out = (float*)d_out;
    float* ws  = (float*)d_ws;

    // Poison the full state-history region (it doubles as the scan's sync
    // medium: sentinel = "not yet produced"). 2 chains * TT * 600 floats.
    hipMemsetAsync(out + 1200, 0xAA, (size_t)2 * TT * 600 * sizeof(float), stream);

    build_emb<<<(TT * INP_P + 255) / 256, 256, 0, stream>>>(ctx, tags, bio, ws + EMB_OFF);
    pad_wih<<<(GG * INP_P + 255) / 256, 256, 0, stream>>>(W_ih, ws + WP_OFF);
    gemm_gi<<<dim3(TT / 64, 29), 256, 0, stream>>>(ws + EMB_OFF, ws + WP_OFF, b_ih, ws + GI_OFF);
    gru_scan<<<2 * NWG, 256, 0, stream>>>(ws + GI_OFF, W_hh, b_hh, out);
    attn_qs<<<BB, 256, 0, stream>>>(W_lin, b_lin, out, ws);
    attn_ctx<<<BB, 256, 0, stream>>>(out, ws);
    attn_gate<<<BB, 256, 0, stream>>>(W_g, b_g, W_f, b_f, ws);
    bcast_attn<<<14400, 256, 0, stream>>>(ws, out);
}

// Round 3
// 23510.709 us; speedup vs baseline: 1.2245x; 1.2245x over previous
//
#include <hip/hip_runtime.h>
#include <math.h>

// Problem constants
#define TT    12288            // B*S flattened scan length
#define HH    600
#define GG    1800             // 3*H
#define INP   303
#define INP_P 304              // padded for float4 alignment
#define BB    32
#define SS    384
#define D2    1200             // 2H
#define D4    2400             // 4H (cat dim)

// Scan partitioning: 75 workgroups per chain, 8 hidden elems each -> 24 W_hh rows
#define NWG  75
#define JPW  8
#define ROWS 24

#define SENT 0xAAAAAAAAu       // harness poison pattern reused as "not yet written" sentinel

// ws layout (float offsets)
#define EMB_OFF    0ull                // also reused as P_OFF after gemm_gi consumes emb
#define WP_OFF     3735552ull          // 12288*304
#define GI_OFF     4282752ull          // + 1800*304
#define HS_OFF     26403808ull
#define Q_OFF      26442208ull
#define CTX_OFF    26480608ull
#define GATED_OFF  26519008ull
#define P_OFF      0ull                // probs (32*384) — emb region is dead by then

// ---------------- K0: build padded emb = [bio_emb[tag], context], and padded W_ih
__global__ void build_emb(const float* __restrict__ ctx, const int* __restrict__ tags,
                          const float* __restrict__ bio, float* __restrict__ emb) {
    int idx = blockIdx.x * 256 + threadIdx.x;
    if (idx >= TT * INP_P) return;
    int row = idx / INP_P;
    int c = idx - row * INP_P;
    float v;
    if (c < 3)        v = bio[tags[row] * 3 + c];
    else if (c < INP) v = ctx[(size_t)row * 300 + (c - 3)];
    else              v = 0.f;
    emb[idx] = v;
}

__global__ void pad_wih(const float* __restrict__ W, float* __restrict__ Wp) {
    int idx = blockIdx.x * 256 + threadIdx.x;
    if (idx >= GG * INP_P) return;
    int r = idx / INP_P, c = idx - r * INP_P;
    Wp[idx] = (c < INP) ? W[(size_t)r * INP + c] : 0.f;
}

// ---------------- K1: gi = emb @ W_ih^T + b_ih   (fp32 tiled GEMM, 64x64 tile, BK=16)
__global__ __launch_bounds__(256) void gemm_gi(const float* __restrict__ A,
                                               const float* __restrict__ Bw,
                                               const float* __restrict__ bias,
                                               float* __restrict__ C) {
    __shared__ float As[16][68];
    __shared__ float Bs[16][68];
    const int tid = threadIdx.x;
    const int bm = blockIdx.x, bn = blockIdx.y;
    const int tx = tid & 15, ty = tid >> 4;
    const int lm = tid >> 2;          // 0..63
    const int lk = (tid & 3) * 4;     // 0,4,8,12
    const int gbase = bn * 64;
    float acc[4][4] = {};
    for (int k0 = 0; k0 < INP_P; k0 += 16) {
        float4 av = *(const float4*)(A + (size_t)(bm * 64 + lm) * INP_P + k0 + lk);
        int grow = gbase + lm;
        float4 bv = make_float4(0.f, 0.f, 0.f, 0.f);
        if (grow < GG) bv = *(const float4*)(Bw + (size_t)grow * INP_P + k0 + lk);
        As[lk + 0][lm] = av.x; As[lk + 1][lm] = av.y; As[lk + 2][lm] = av.z; As[lk + 3][lm] = av.w;
        Bs[lk + 0][lm] = bv.x; Bs[lk + 1][lm] = bv.y; Bs[lk + 2][lm] = bv.z; Bs[lk + 3][lm] = bv.w;
        __syncthreads();
#pragma unroll
        for (int kk = 0; kk < 16; ++kk) {
            float4 a4 = *(const float4*)&As[kk][tx * 4];
            float4 b4 = *(const float4*)&Bs[kk][ty * 4];
            acc[0][0] += a4.x * b4.x; acc[0][1] += a4.x * b4.y; acc[0][2] += a4.x * b4.z; acc[0][3] += a4.x * b4.w;
            acc[1][0] += a4.y * b4.x; acc[1][1] += a4.y * b4.y; acc[1][2] += a4.y * b4.z; acc[1][3] += a4.y * b4.w;
            acc[2][0] += a4.z * b4.x; acc[2][1] += a4.z * b4.y; acc[2][2] += a4.z * b4.z; acc[2][3] += a4.z * b4.w;
            acc[3][0] += a4.w * b4.x; acc[3][1] += a4.w * b4.y; acc[3][2] += a4.w * b4.z; acc[3][3] += a4.w * b4.w;
        }
        __syncthreads();
    }
    int g0 = gbase + ty * 4;
    if (g0 < GG) {
        float4 bi4 = *(const float4*)(bias + g0);
#pragma unroll
        for (int i = 0; i < 4; ++i) {
            float4 v = make_float4(acc[i][0] + bi4.x, acc[i][1] + bi4.y,
                                   acc[i][2] + bi4.z, acc[i][3] + bi4.w);
            *(float4*)(C + (size_t)(bm * 64 + tx * 4 + i) * GG + g0) = v;
        }
    }
}

// ---------------- K2: the two sequential GRU scans.
// Sync protocol: the state history itself is the token (write-once sentinel).
// W_hh slice lives in REGISTERS: lane (rg,cc) owns rows {rg, 8+rg, 16+rg} of
// the wg's 24-row slice, cols [cc*20, cc*20+20) -> 15 float4 VGPRs. Per step
// only h flows through LDS (20 ds_read_b128 wave-instructions total).
__global__ __launch_bounds__(256) void gru_scan(const float* __restrict__ gi,
                                                const float* __restrict__ Whh,
                                                const float* __restrict__ bhh,
                                                float* __restrict__ out) {
    __shared__ __align__(16) float h_lds[600];
    __shared__ __align__(16) float partials[720];   // [gate][rg][cc] = gate*240+rg*30+cc
    __shared__ float gi_lds[ROWS];
    __shared__ float bhh_lds[ROWS];

    const int tid = threadIdx.x;
    const int chain = blockIdx.x / NWG;   // 0 = fwd, 1 = bwd
    const int wg = blockIdx.x % NWG;
    const int j0 = wg * JPW;

    float* statesOut = out + 1200 + (size_t)chain * TT * 600;
    unsigned* statesU = (unsigned*)statesOut;

    // ---- one-time: W_hh slice into registers
    const int rg = (tid < 240) ? tid / 30 : 0;     // output index within wg slice
    const int cc = (tid < 240) ? tid % 30 : 0;     // col-chunk (20 floats)
    float4 wreg[3][5];
    if (tid < 240) {
#pragma unroll
        for (int g = 0; g < 3; ++g) {
            int row = g * 600 + j0 + rg;
#pragma unroll
            for (int u = 0; u < 5; ++u)
                wreg[g][u] = *(const float4*)(Whh + (size_t)row * 600 + cc * 20 + u * 4);
        }
    }
    if (tid < ROWS) {
        int row = (tid >> 3) * 600 + j0 + (tid & 7);   // gate=tid>>3, j=tid&7
        bhh_lds[tid] = bhh[row];
    }

    const int w2 = tid + 512;
    const int w2c = (w2 < 600) ? w2 : 0;
    int si = 0, bi = 0;

    for (int t = 0; t < TT; ++t) {
        // prefetch this wg's gi slice (depends only on t) — in flight during poll
        float gi_reg = 0.f;
        if (tid < ROWS) {
            int gi_row = (chain == 0) ? t : (bi * SS + (SS - 1) - si);
            gi_reg = gi[(size_t)gi_row * GG + (tid >> 3) * 600 + j0 + (tid & 7)];
        }
        if (t == 0) {
            h_lds[tid] = 0.f;
            h_lds[tid + 256] = 0.f;
            if (w2 < 600) h_lds[w2] = 0.f;
        } else {
            const unsigned* hu = statesU + (size_t)(t - 1) * 600;
            unsigned b0 = SENT, b1 = SENT, b2 = (w2 < 600) ? SENT : 0u;
            for (;;) {
                if (b0 == SENT) b0 = __hip_atomic_load(hu + tid,       __ATOMIC_RELAXED, __HIP_MEMORY_SCOPE_AGENT);
                if (b1 == SENT) b1 = __hip_atomic_load(hu + tid + 256, __ATOMIC_RELAXED, __HIP_MEMORY_SCOPE_AGENT);
                if (b2 == SENT) b2 = __hip_atomic_load(hu + w2c,       __ATOMIC_RELAXED, __HIP_MEMORY_SCOPE_AGENT);
                if (b0 != SENT && b1 != SENT && b2 != SENT) break;
                __builtin_amdgcn_s_sleep(1);
            }
            h_lds[tid] = __uint_as_float(b0);
            h_lds[tid + 256] = __uint_as_float(b1);
            if (w2 < 600) h_lds[w2] = __uint_as_float(b2);
        }
        __syncthreads();                      // sync1: h staged
        // matvec: lane computes 3 partial dots (r/z/n of output rg) over 20 cols
        if (tid < 240) {
            const float4* h4p = (const float4*)h_lds;
            float a0 = 0.f, a1 = 0.f, a2 = 0.f;
#pragma unroll
            for (int u = 0; u < 5; ++u) {
                float4 h4 = h4p[cc * 5 + u];
                a0 += wreg[0][u].x * h4.x + wreg[0][u].y * h4.y + wreg[0][u].z * h4.z + wreg[0][u].w * h4.w;
                a1 += wreg[1][u].x * h4.x + wreg[1][u].y * h4.y + wreg[1][u].z * h4.z + wreg[1][u].w * h4.w;
                a2 += wreg[2][u].x * h4.x + wreg[2][u].y * h4.y + wreg[2][u].z * h4.z + wreg[2][u].w * h4.w;
            }
            partials[tid] = a0;
            partials[240 + tid] = a1;
            partials[480 + tid] = a2;
        }
        if (tid < ROWS) gi_lds[tid] = gi_reg;
        __syncthreads();                      // sync2: partials + gi ready
        // wave 0: reduce 30 partials per (gate,j), shfl z/n to lanes 0..7, gates
        if (tid < 64) {
            float s = 0.f;
            if (tid < 24) {
                const float2* p2 = (const float2*)(partials + (tid >> 3) * 240 + (tid & 7) * 30);
                float s0 = 0.f, s1 = 0.f;
#pragma unroll
                for (int c = 0; c < 15; c += 3) {
                    float2 x = p2[c], y = p2[c + 1], z = p2[c + 2];
                    s0 += x.x + x.y; s1 += y.x + y.y; s0 += z.x + z.y;
                }
                s = s0 + s1 + bhh_lds[tid];
            }
            float dz = __shfl(s, tid + 8);
            float dn = __shfl(s, tid + 16);
            if (tid < JPW) {
                int jg = j0 + tid;
                float r = 1.f / (1.f + __expf(-(gi_lds[tid] + s)));
                float z = 1.f / (1.f + __expf(-(gi_lds[8 + tid] + dz)));
                float x = gi_lds[16 + tid] + r * dn;
                float e = __expf(-2.f * fabsf(x));
                float n = copysignf((1.f - e) / (1.f + e), x);
                float hnew = (1.f - z) * n + z * h_lds[jg];
                if (__float_as_uint(hnew) == SENT) hnew = __uint_as_float(SENT + 1u);
                __hip_atomic_store(statesU + (size_t)t * 600 + jg, __float_as_uint(hnew),
                                   __ATOMIC_RELAXED, __HIP_MEMORY_SCOPE_AGENT);
                if (t == TT - 1) out[chain * 600 + jg] = hnew;   // final = [h_f, h_b]
            }
        }
        if (++si == SS) { si = 0; ++bi; }
    }
}

// ---------------- K3a: hs gather + q = hs @ W_lin^T + b_lin  (grid 32 x 20)
__global__ __launch_bounds__(256) void attn_qs(const float* __restrict__ Wlin,
                                               const float* __restrict__ blin,
                                               const float* __restrict__ outp,
                                               float* __restrict__ ws) {
    __shared__ float hs_lds[1200];
    const int bi = blockIdx.x, ob = blockIdx.y * 60, tid = threadIdx.x;
    const float* fwdS = outp + 1200;
    const float* bwdS = outp + 1200 + (size_t)TT * 600;
    size_t row = (size_t)(bi * SS + SS - 1) * 600;
    for (int k = tid; k < 600; k += 256) {
        hs_lds[k] = fwdS[row + k];
        hs_lds[600 + k] = bwdS[row + k];
    }
    __syncthreads();
    if (blockIdx.y == 0) {
        float* ws_hs = ws + HS_OFF;
        for (int k = tid; k < 1200; k += 256) ws_hs[bi * 1200 + k] = hs_lds[k];
    }
    float* ws_q = ws + Q_OFF;
    const int wave = tid >> 6, lane = tid & 63;
    for (int i = 0; i < 15; ++i) {
        int o = ob + wave * 15 + i;
        const float* wr = Wlin + (size_t)o * 1200;
        float acc = 0.f;
        for (int k = lane; k < 1200; k += 64) acc += hs_lds[k] * wr[k];
        for (int off = 32; off > 0; off >>= 1) acc += __shfl_down(acc, off);
        if (lane == 0) ws_q[bi * 1200 + o] = acc + blin[o];
    }
}

// ---------------- K3b: logits + softmax -> probs
__global__ __launch_bounds__(256) void attn_logits(const float* __restrict__ outp,
                                                   float* __restrict__ ws) {
    __shared__ float q_lds[1200];
    __shared__ float p_lds[SS];
    __shared__ float red[8];
    const int bi = blockIdx.x, tid = threadIdx.x;
    const float* fwdS = outp + 1200;
    const float* bwdS = outp + 1200 + (size_t)TT * 600;
    const float* ws_q = ws + Q_OFF;
    for (int k = tid; k < 1200; k += 256) q_lds[k] = ws_q[bi * 1200 + k];
    __syncthreads();
    const int wave = tid >> 6, lane = tid & 63;
    for (int s = wave; s < SS; s += 4) {
        size_t base = (size_t)(bi * SS + s) * 600;
        float acc = 0.f;
        for (int k = lane; k < 600; k += 64)
            acc += q_lds[k] * fwdS[base + k] + q_lds[600 + k] * bwdS[base + k];
        for (int off = 32; off > 0; off >>= 1) acc += __shfl_down(acc, off);
        if (lane == 0) p_lds[s] = acc;
    }
    __syncthreads();
    float m = -1e30f;
    for (int i = tid; i < SS; i += 256) m = fmaxf(m, p_lds[i]);
    for (int off = 32; off > 0; off >>= 1) m = fmaxf(m, __shfl_down(m, off));
    if (lane == 0) red[wave] = m;
    __syncthreads();
    m = fmaxf(fmaxf(red[0], red[1]), fmaxf(red[2], red[3]));
    float ssum = 0.f;
    for (int i = tid; i < SS; i += 256) ssum += expf(p_lds[i] - m);
    for (int off = 32; off > 0; off >>= 1) ssum += __shfl_down(ssum, off);
    __syncthreads();
    if (lane == 0) red[wave] = ssum;
    __syncthreads();
    ssum = red[0] + red[1] + red[2] + red[3];
    float inv = 1.f / ssum;
    float* ws_p = ws + P_OFF;
    for (int i = tid; i < SS; i += 256) ws_p[bi * SS + i] = expf(p_lds[i] - m) * inv;
}

// ---------------- K3c: ctx = probs @ states  (grid 32 x 5, 240 threads active)
__global__ __launch_bounds__(256) void attn_ctxv(const float* __restrict__ outp,
                                                 float* __restrict__ ws) {
    __shared__ float p_lds[SS];
    const int bi = blockIdx.x, d0 = blockIdx.y * 240, tid = threadIdx.x;
    const float* ws_p = ws + P_OFF;
    for (int k = tid; k < SS; k += 256) p_lds[k] = ws_p[bi * SS + k];
    __syncthreads();
    if (tid >= 240) return;
    const int d = d0 + tid;
    const float* fwdS = outp + 1200;
    const float* bwdS = outp + 1200 + (size_t)TT * 600;
    const float* Sb = (d < 600) ? (fwdS + d) : (bwdS + d - 600);
    size_t rbase = (size_t)bi * SS * 600;
    float a0 = 0.f, a1 = 0.f, a2 = 0.f, a3 = 0.f;
#pragma unroll 4
    for (int s = 0; s < SS; s += 4) {
        a0 += p_lds[s + 0] * Sb[rbase + (size_t)(s + 0) * 600];
        a1 += p_lds[s + 1] * Sb[rbase + (size_t)(s + 1) * 600];
        a2 += p_lds[s + 2] * Sb[rbase + (size_t)(s + 2) * 600];
        a3 += p_lds[s + 3] * Sb[rbase + (size_t)(s + 3) * 600];
    }
    (ws + CTX_OFF)[bi * 1200 + d] = (a0 + a1) + (a2 + a3);
}

// ---------------- K3d: g/f gates over cat=[ctx,hs]  (grid 32 x 20)
__global__ __launch_bounds__(256) void attn_gate(const float* __restrict__ Wg,
                                                 const float* __restrict__ bg,
                                                 const float* __restrict__ Wf,
                                                 const float* __restrict__ bf,
                                                 float* __restrict__ ws) {
    __shared__ float cat_lds[2400];
    const int bi = blockIdx.x, ob = blockIdx.y * 60, tid = threadIdx.x;
    const float* ws_ctx = ws + CTX_OFF;
    const float* ws_hs = ws + HS_OFF;
    for (int k = tid; k < 1200; k += 256) {
        cat_lds[k] = ws_ctx[bi * 1200 + k];
        cat_lds[1200 + k] = ws_hs[bi * 1200 + k];
    }
    __syncthreads();
    float* ws_g = ws + GATED_OFF;
    const int wave = tid >> 6, lane = tid & 63;
    for (int i = 0; i < 15; ++i) {
        int o = ob + wave * 15 + i;
        const float* wg = Wg + (size_t)o * D4;
        const float* wf = Wf + (size_t)o * D4;
        float ag = 0.f, af = 0.f;
        for (int k = lane; k < D4; k += 64) {
            float c = cat_lds[k];
            ag += c * wg[k];
            af += c * wf[k];
        }
        for (int off = 32; off > 0; off >>= 1) {
            ag += __shfl_down(ag, off);
            af += __shfl_down(af, off);
        }
        if (lane == 0) {
            float g = 1.f / (1.f + expf(-(ag + bg[o])));
            float f = tanhf(af + bf[o]);
            ws_g[bi * 1200 + o] = g * f + (1.f - g) * cat_lds[1200 + o];
        }
    }
}

// ---------------- K3e: broadcast gated -> attn output (overwrites the states scratch)
__global__ void bcast_attn(const float* __restrict__ ws, float* __restrict__ outp) {
    int idx = blockIdx.x * 256 + threadIdx.x;     // float4 index, exactly 3686400
    const float4* g4 = (const float4*)(ws + GATED_OFF);
    float4* o4 = (float4*)outp;
    int row = idx / 300;          // bi*384+si
    int d4 = idx - row * 300;
    int bi = row / SS;
    o4[300 + idx] = g4[bi * 300 + d4];
}

extern "C" void kernel_launch(void* const* d_in, const int* in_sizes, int n_in,
                              void* d_out, int out_size, void* d_ws, size_t ws_size,
                              hipStream_t stream) {
    const float* ctx   = (const float*)d_in[0];
    const int*   tags  = (const int*)d_in[1];
    const float* bio   = (const float*)d_in[2];
    const float* W_ih  = (const float*)d_in[3];
    const float* b_ih  = (const float*)d_in[4];
    const float* W_hh  = (const float*)d_in[5];
    const float* b_hh  = (const float*)d_in[6];
    const float* W_lin = (const float*)d_in[7];
    const float* b_lin = (const float*)d_in[8];
    const float* W_g   = (const float*)d_in[9];
    const float* b_g   = (const float*)d_in[10];
    const float* W_f   = (const float*)d_in[11];
    const float* b_f   = (const float*)d_in[12];
    float* out = (float*)d_out;
    float* ws  = (float*)d_ws;

    // Poison the full state-history region (it doubles as the scan's sync
    // medium: sentinel = "not yet produced"). 2 chains * TT * 600 floats.
    hipMemsetAsync(out + 1200, 0xAA, (size_t)2 * TT * 600 * sizeof(float), stream);

    build_emb<<<(TT * INP_P + 255) / 256, 256, 0, stream>>>(ctx, tags, bio, ws + EMB_OFF);
    pad_wih<<<(GG * INP_P + 255) / 256, 256, 0, stream>>>(W_ih, ws + WP_OFF);
    gemm_gi<<<dim3(TT / 64, 29), 256, 0, stream>>>(ws + EMB_OFF, ws + WP_OFF, b_ih, ws + GI_OFF);
    gru_scan<<<2 * NWG, 256, 0, stream>>>(ws + GI_OFF, W_hh, b_hh, out);
    attn_qs<<<dim3(BB, 20), 256, 0, stream>>>(W_lin, b_lin, out, ws);
    attn_logits<<<BB, 256, 0, stream>>>(out, ws);
    attn_ctxv<<<dim3(BB, 5), 256, 0, stream>>>(out, ws);
    attn_gate<<<dim3(BB, 20), 256, 0, stream>>>(W_g, b_g, W_f, b_f, ws);
    bcast_attn<<<14400, 256, 0, stream>>>(ws, out);
}